// Round 1
// baseline (611.063 us; speedup 1.0000x reference)
//
#include <hip/hip_runtime.h>
#include <math.h>

#define NB    8
#define LQ    300
#define CC    256
#define HEADS 8
#define NLVL  4
#define NPTS  8
#define DH    32
#define LEN_IN 21760
#define NQ    (NB*LQ)     // 2400
#define MH    128
#define MW    128

typedef __attribute__((ext_vector_type(8))) short bf16x8;
typedef __attribute__((ext_vector_type(8))) unsigned short ushort8;
typedef __attribute__((ext_vector_type(4))) float f32x4;
typedef unsigned short ushort;
typedef unsigned int uint;

#define AS1 __attribute__((address_space(1)))
#define AS3 __attribute__((address_space(3)))

static __device__ __forceinline__ ushort f2bf(float f) {
    uint u = __builtin_bit_cast(uint, f);
    uint r = (u + 0x7fffu + ((u >> 16) & 1u)) >> 16;   // RNE
    return (ushort)r;
}
static __device__ __forceinline__ float bf2f(ushort u) {
    return __builtin_bit_cast(float, ((uint)u) << 16);
}

// ---------------------------------------------------------------------------
// W_val (k-major 256x256 f32) -> Bt (n-major 256x256 bf16)
// ---------------------------------------------------------------------------
__global__ void transpose_cast_w(const float* __restrict__ W, ushort* __restrict__ Bt) {
    int n = blockIdx.x, k = threadIdx.x;
    Bt[n * CC + k] = f2bf(W[(size_t)k * CC + n]);
}

// ---------------------------------------------------------------------------
// MFMA value GEMM: value[M,256](bf16) = A[M,256](f32) @ W + bias.
// Barrier-free K-loop: whole 128x256 B-tile preloaded to LDS once (XOR-
// swizzled, 64KB); A fragments loaded straight from global into registers
// (f32 -> bf16 in-reg), 1-deep prefetch pipeline; 16 MFMA per K-step.
// ---------------------------------------------------------------------------
// byte offset into swizzled B tile: row-major [128][512B], 16B-unit XOR swizzle
#define BSWZ(r, cb) (((r) << 9) + ((cb) ^ (((r) & 7) << 4)))

__global__ __launch_bounds__(256) void gemm_mfma_value(
    const float* __restrict__ A, const ushort* __restrict__ Bt,
    const float* __restrict__ bias, ushort* __restrict__ C, int M)
{
    __shared__ ushort Bs[128 * 256];          // 64 KB, swizzled
    char* bs = (char*)Bs;
    const int tid  = threadIdx.x;
    const int wave = tid >> 6, lane = tid & 63;
    const int bm = blockIdx.x * 128;
    const int bn = blockIdx.y * 128;
    const int wm = (wave >> 1) * 64, wn = (wave & 1) * 64;

    // ---- one-time: stage B tile (128 n-rows x 256 k) into LDS, swizzled ----
    #pragma unroll
    for (int it = 0; it < 16; ++it) {
        int idx = it * 256 + tid;             // 0..4095 16B-chunks
        int r   = idx >> 5;                   // n-row 0..127
        int c8  = idx & 31;                   // 16B chunk within row
        ushort8 v = *(const ushort8*)(Bt + (size_t)(bn + r) * CC + c8 * 8);
        *(ushort8*)(bs + BSWZ(r, c8 * 16)) = v;
    }
    __syncthreads();

    f32x4 acc[4][4] = {};
    const int fr = lane & 15, kg = lane >> 4;
    const float* aA = A + (size_t)(bm + wm + fr) * CC + kg * 8;

    // prefetch kt=0 A fragments (8 f32 per i => two float4 each)
    float4 fA[4][2];
    #pragma unroll
    for (int i = 0; i < 4; ++i) {
        const float* ap = aA + (size_t)(i * 16) * CC;
        fA[i][0] = *(const float4*)(ap);
        fA[i][1] = *(const float4*)(ap + 4);
    }

    #pragma unroll
    for (int kt = 0; kt < 8; ++kt) {
        // B fragments from swizzled LDS
        bf16x8 bfv[4];
        #pragma unroll
        for (int j = 0; j < 4; ++j)
            bfv[j] = *(const bf16x8*)(bs + BSWZ(wn + j * 16 + fr, kt * 64 + kg * 16));

        // convert current A prefetch to bf16 fragments
        bf16x8 af[4];
        #pragma unroll
        for (int i = 0; i < 4; ++i) {
            ushort8 u;
            u[0] = f2bf(fA[i][0].x); u[1] = f2bf(fA[i][0].y);
            u[2] = f2bf(fA[i][0].z); u[3] = f2bf(fA[i][0].w);
            u[4] = f2bf(fA[i][1].x); u[5] = f2bf(fA[i][1].y);
            u[6] = f2bf(fA[i][1].z); u[7] = f2bf(fA[i][1].w);
            af[i] = __builtin_bit_cast(bf16x8, u);
        }

        // issue next K-step's A loads before the MFMAs (1-deep pipeline)
        if (kt < 7) {
            #pragma unroll
            for (int i = 0; i < 4; ++i) {
                const float* ap = aA + (size_t)(i * 16) * CC + (kt + 1) * 32;
                fA[i][0] = *(const float4*)(ap);
                fA[i][1] = *(const float4*)(ap + 4);
            }
        }

        #pragma unroll
        for (int i = 0; i < 4; ++i)
            #pragma unroll
            for (int j = 0; j < 4; ++j)
                acc[i][j] = __builtin_amdgcn_mfma_f32_16x16x32_bf16(af[i], bfv[j], acc[i][j], 0, 0, 0);
    }

    const int col0 = lane & 15, rq = (lane >> 4) * 4;
    #pragma unroll
    for (int j = 0; j < 4; ++j) {
        const int col = bn + wn + j * 16 + col0;
        const float bv = bias[col];
        #pragma unroll
        for (int i = 0; i < 4; ++i) {
            const int row = bm + wm + i * 16 + rq;
            #pragma unroll
            for (int r = 0; r < 4; ++r)
                C[(size_t)(row + r) * CC + col] = f2bf(acc[i][j][r] + bv);
        }
    }
}

// ---------------------------------------------------------------------------
// Generic tiled f32 GEMM with bias (small GEMMs)
// ---------------------------------------------------------------------------
#define TM 64
#define TN 64
#define TK 16

__global__ __launch_bounds__(256) void gemm_bias_kernel(
    const float* __restrict__ A, const float* __restrict__ B,
    const float* __restrict__ bias, float* __restrict__ Cmat,
    int M, int N, int K)
{
    __shared__ float As[TK][TM + 4];
    __shared__ float Bs[TK][TN + 4];
    const int tid = threadIdx.x;
    const int bm = blockIdx.x * TM;
    const int bn = blockIdx.y * TN;
    const int tm = (tid >> 4) << 2;
    const int tn = (tid & 15) << 2;
    float acc[4][4] = {};

    for (int k0 = 0; k0 < K; k0 += TK) {
        #pragma unroll
        for (int i = 0; i < 4; ++i) {
            int idx = tid + i * 256;
            int m = idx >> 4;
            int k = idx & 15;
            int gm = bm + m;
            float v = 0.f;
            if (gm < M) v = A[(size_t)gm * K + k0 + k];
            As[k][m] = v;
        }
        #pragma unroll
        for (int i = 0; i < 4; ++i) {
            int idx = tid + i * 256;
            int k = idx >> 6;
            int n = idx & 63;
            int gn = bn + n;
            float v = 0.f;
            if (gn < N) v = B[(size_t)(k0 + k) * N + gn];
            Bs[k][n] = v;
        }
        __syncthreads();
        #pragma unroll
        for (int k = 0; k < TK; ++k) {
            float a[4], b[4];
            #pragma unroll
            for (int i = 0; i < 4; ++i) a[i] = As[k][tm + i];
            #pragma unroll
            for (int j = 0; j < 4; ++j) b[j] = Bs[k][tn + j];
            #pragma unroll
            for (int i = 0; i < 4; ++i)
                #pragma unroll
                for (int j = 0; j < 4; ++j)
                    acc[i][j] = fmaf(a[i], b[j], acc[i][j]);
        }
        __syncthreads();
    }

    #pragma unroll
    for (int i = 0; i < 4; ++i) {
        int m = bm + tm + i;
        if (m >= M) continue;
        #pragma unroll
        for (int j = 0; j < 4; ++j) {
            int n = bn + tn + j;
            if (n < N) Cmat[(size_t)m * N + n] = acc[i][j] + bias[n];
        }
    }
}

// ---------------------------------------------------------------------------
// bbox kernel: one block per (n,q); scan 128x128 mask, write box[4] to ws.
// ---------------------------------------------------------------------------
__global__ __launch_bounds__(256) void bbox_kernel(
    const float* __restrict__ masks, float* __restrict__ boxes)
{
    const int b   = blockIdx.x;
    const int tid = threadIdx.x;
    const float4* m4 = (const float4*)(masks + (size_t)b * (MH * MW));

    int wmin = MW, wmax = -1, hmin = MH, hmax = -1;
    #pragma unroll
    for (int it = 0; it < 16; ++it) {
        int i = tid + it * 256;
        float4 v = m4[i];
        int base = i << 2;
        int h = base >> 7;
        int w0 = base & 127;
        bool a0 = v.x > 0.f, a1 = v.y > 0.f, a2 = v.z > 0.f, a3 = v.w > 0.f;
        if (a0 | a1 | a2 | a3) { hmin = min(hmin, h); hmax = max(hmax, h); }
        if (a0) { wmin = min(wmin, w0);     wmax = max(wmax, w0);     }
        if (a1) { wmin = min(wmin, w0 + 1); wmax = max(wmax, w0 + 1); }
        if (a2) { wmin = min(wmin, w0 + 2); wmax = max(wmax, w0 + 2); }
        if (a3) { wmin = min(wmin, w0 + 3); wmax = max(wmax, w0 + 3); }
    }
    #pragma unroll
    for (int off = 32; off; off >>= 1) {
        wmin = min(wmin, __shfl_xor(wmin, off));
        wmax = max(wmax, __shfl_xor(wmax, off));
        hmin = min(hmin, __shfl_xor(hmin, off));
        hmax = max(hmax, __shfl_xor(hmax, off));
    }
    __shared__ int s_wmin[4], s_wmax[4], s_hmin[4], s_hmax[4];
    const int wave = tid >> 6;
    if ((tid & 63) == 0) {
        s_wmin[wave] = wmin; s_wmax[wave] = wmax;
        s_hmin[wave] = hmin; s_hmax[wave] = hmax;
    }
    __syncthreads();
    if (tid == 0) {
        int a = MW, bx = -1, c = MH, d = -1;
        #pragma unroll
        for (int i = 0; i < 4; ++i) {
            a = min(a, s_wmin[i]); bx = max(bx, s_wmax[i]);
            c = min(c, s_hmin[i]); d = max(d, s_hmax[i]);
        }
        float4 box;
        if (bx >= 0) {
            float x0 = a * (1.f / MW), x1 = (bx + 1) * (1.f / MW);
            float y0 = c * (1.f / MH), y1 = (d + 1) * (1.f / MH);
            box = make_float4((x0 + x1) * 0.5f, (y0 + y1) * 0.5f, x1 - x0, y1 - y0);
        } else {
            box = make_float4(0.f, 0.f, 0.f, 0.f);
        }
        *(float4*)(boxes + (size_t)b * 4) = box;
    }
}

// ---------------------------------------------------------------------------
// Sampling: one block (512 threads) per (n,q). Phase 1 (tid<256): loc, gate,
// softmax. Phase 2: half=tid>>8 handles 2 levels; branchless clamped corner
// loads from bf16 value; LDS reduce across halves.
// ---------------------------------------------------------------------------
template<int WL>
static __device__ __forceinline__ float sample_level(
    const ushort* __restrict__ vbase, int st,
    const float* __restrict__ s_lx, const float* __restrict__ s_ly,
    const float* __restrict__ s_w, int ptbase)
{
    float acc = 0.f;
    #pragma unroll
    for (int p = 0; p < NPTS; ++p) {
        const int pt = ptbase + p;
        const float fx = s_lx[pt] * WL - 0.5f;
        const float fy = s_ly[pt] * WL - 0.5f;
        const float pw = s_w[pt];
        const float x0f = floorf(fx), y0f = floorf(fy);
        const float wx = fx - x0f, wy = fy - y0f;
        const int x0 = (int)x0f, y0 = (int)y0f;
        const int x1 = x0 + 1, y1 = y0 + 1;
        const int x0c = min(max(x0, 0), WL - 1);
        const int x1c = min(max(x1, 0), WL - 1);
        const int y0c = min(max(y0, 0), WL - 1);
        const int y1c = min(max(y1, 0), WL - 1);
        const float vx0 = (x0 >= 0 && x0 < WL) ? 1.f : 0.f;
        const float vx1 = (x1 >= 0 && x1 < WL) ? 1.f : 0.f;
        const float vy0 = (y0 >= 0 && y0 < WL) ? 1.f : 0.f;
        const float vy1 = (y1 >= 0 && y1 < WL) ? 1.f : 0.f;
        const ushort* r0 = vbase + (size_t)(st + y0c * WL) * CC;
        const ushort* r1 = vbase + (size_t)(st + y1c * WL) * CC;
        const float v00 = bf2f(r0[(size_t)x0c * CC]);
        const float v01 = bf2f(r0[(size_t)x1c * CC]);
        const float v10 = bf2f(r1[(size_t)x0c * CC]);
        const float v11 = bf2f(r1[(size_t)x1c * CC]);
        const float w00 = vx0 * vy0 * (1.f - wx) * (1.f - wy);
        const float w01 = vx1 * vy0 * wx * (1.f - wy);
        const float w10 = vx0 * vy1 * (1.f - wx) * wy;
        const float w11 = vx1 * vy1 * wx * wy;
        acc += pw * (w00 * v00 + w01 * v01 + w10 * v10 + w11 * v11);
    }
    return acc;
}

__global__ __launch_bounds__(512) void sample_kernel(
    const float* __restrict__ masks,   // (NQ, 128*128)
    const ushort* __restrict__ value,  // (NB, LEN_IN, 256) bf16
    const float* __restrict__ offs,    // (NQ, 512)
    const float* __restrict__ attw,    // (NQ, 256)
    const float* __restrict__ boxes,   // (NQ, 4)
    float* __restrict__ samp)          // (NQ, 256)
{
    const int b   = blockIdx.x;
    const int n   = b / LQ;
    const int tid = threadIdx.x;

    __shared__ float s_lx[256], s_ly[256], s_w[256], s_acc[256];

    if (tid < 256) {
        const float4 box = *(const float4*)(boxes + (size_t)b * 4);
        const float ox = offs[(size_t)b * 512 + tid * 2 + 0];
        const float oy = offs[(size_t)b * 512 + tid * 2 + 1];
        const float lx = box.x + ox * (1.f / NPTS) * box.z * 0.5f;
        const float ly = box.y + oy * (1.f / NPTS) * box.w * 0.5f;
        int px = (int)(lx * MW); px = min(max(px, 0), MW - 1);
        int py = (int)(ly * MH); py = min(max(py, 0), MH - 1);
        const float pin = (masks[(size_t)b * (MH * MW) + py * MW + px] > 0.f) ? 1.f : 0.f;
        const float logit = attw[(size_t)b * 256 + tid] * pin;
        float mx = logit;
        #pragma unroll
        for (int off = 16; off; off >>= 1) mx = fmaxf(mx, __shfl_xor(mx, off, 32));
        const float e = expf(logit - mx);
        float ssum = e;
        #pragma unroll
        for (int off = 16; off; off >>= 1) ssum += __shfl_xor(ssum, off, 32);
        s_lx[tid] = lx; s_ly[tid] = ly; s_w[tid] = e / ssum;
    }
    __syncthreads();

    const int half = tid >> 8;
    const int h = (tid >> 5) & 7, d = tid & 31;
    const ushort* vbase = value + (size_t)n * LEN_IN * CC + h * DH + d;
    float acc;
    if (half == 0) {
        acc  = sample_level<128>(vbase, 0,     s_lx, s_ly, s_w, (h * NLVL + 0) * NPTS);
        acc += sample_level< 64>(vbase, 16384, s_lx, s_ly, s_w, (h * NLVL + 1) * NPTS);
        s_acc[tid] = acc;
    } else {
        acc  = sample_level< 32>(vbase, 20480, s_lx, s_ly, s_w, (h * NLVL + 2) * NPTS);
        acc += sample_level< 16>(vbase, 21504, s_lx, s_ly, s_w, (h * NLVL + 3) * NPTS);
    }
    __syncthreads();
    if (half == 1)
        samp[(size_t)b * 256 + (tid - 256)] = acc + s_acc[tid - 256];
}

// ---------------------------------------------------------------------------
extern "C" void kernel_launch(void* const* d_in, const int* in_sizes, int n_in,
                              void* d_out, int out_size, void* d_ws, size_t ws_size,
                              hipStream_t stream)
{
    const float* query  = (const float*)d_in[0];
    const float* masks  = (const float*)d_in[2];
    const float* flat   = (const float*)d_in[4];
    const float* W_off  = (const float*)d_in[8];
    const float* b_off  = (const float*)d_in[9];
    const float* W_attn = (const float*)d_in[10];
    const float* b_attn = (const float*)d_in[11];
    const float* W_val  = (const float*)d_in[12];
    const float* b_val  = (const float*)d_in[13];
    const float* W_out  = (const float*)d_in[14];
    const float* b_out  = (const float*)d_in[15];
    float* out = (float*)d_out;

    float*  offs  = (float*)d_ws;                        // 2400*512
    float*  attw  = offs + (size_t)NQ * 512;             // 2400*256
    float*  samp  = attw + (size_t)NQ * 256;             // 2400*256
    float*  boxes = samp + (size_t)NQ * 256;             // 2400*4
    ushort* value = (ushort*)(boxes + (size_t)NQ * 4);   // 174080*256 bf16
    ushort* Bt    = value + (size_t)NB * LEN_IN * CC;    // 256*256 bf16

    const int Mval = NB * LEN_IN;                        // 174080

    transpose_cast_w<<<CC, CC, 0, stream>>>(W_val, Bt);
    gemm_mfma_value<<<dim3(Mval / 128, CC / 128), 256, 0, stream>>>(
        flat, Bt, b_val, value, Mval);
    gemm_bias_kernel<<<dim3((NQ + TM - 1) / TM, 512 / TN), 256, 0, stream>>>(
        query, W_off, b_off, offs, NQ, 512, CC);
    gemm_bias_kernel<<<dim3((NQ + TM - 1) / TM, CC / TN), 256, 0, stream>>>(
        query, W_attn, b_attn, attw, NQ, CC, CC);
    bbox_kernel<<<NQ, 256, 0, stream>>>(masks, boxes);
    sample_kernel<<<NQ, 512, 0, stream>>>(masks, value, offs, attw, boxes, samp);
    gemm_bias_kernel<<<dim3((NQ + TM - 1) / TM, CC / TN), 256, 0, stream>>>(
        samp, W_out, b_out, out, NQ, CC, CC);
}

// Round 3
// 608.062 us; speedup vs baseline: 1.0049x; 1.0049x over previous
//
#include <hip/hip_runtime.h>
#include <math.h>

#define NB    8
#define LQ    300
#define CC    256
#define HEADS 8
#define NLVL  4
#define NPTS  8
#define DH    32
#define LEN_IN 21760
#define NQ    (NB*LQ)     // 2400
#define MH    128
#define MW    128

typedef __attribute__((ext_vector_type(8))) short bf16x8;
typedef __attribute__((ext_vector_type(8))) unsigned short ushort8;
typedef __attribute__((ext_vector_type(4))) float f32x4;
typedef unsigned short ushort;
typedef unsigned int uint;

#define AS1 __attribute__((address_space(1)))
#define AS3 __attribute__((address_space(3)))

static __device__ __forceinline__ ushort f2bf(float f) {
    uint u = __builtin_bit_cast(uint, f);
    uint r = (u + 0x7fffu + ((u >> 16) & 1u)) >> 16;   // RNE
    return (ushort)r;
}
static __device__ __forceinline__ float bf2f(ushort u) {
    return __builtin_bit_cast(float, ((uint)u) << 16);
}

// ---------------------------------------------------------------------------
// W_val (k-major 256x256 f32) -> Bt (n-major 256x256 bf16)
// ---------------------------------------------------------------------------
__global__ void transpose_cast_w(const float* __restrict__ W, ushort* __restrict__ Bt) {
    int n = blockIdx.x, k = threadIdx.x;
    Bt[n * CC + k] = f2bf(W[(size_t)k * CC + n]);
}

// ---------------------------------------------------------------------------
// MFMA value GEMM: value[M,256](bf16) = A[M,256](f32) @ W + bias.
// Barrier-free K-loop: whole 128x256 B-tile in LDS (XOR-swizzled, staged
// once); A loaded straight to registers with an explicit 2-deep ping-pong
// (pA/pB, static-indexed) so 8-16 float4 loads stay in flight per wave.
// __launch_bounds__(256,2): 8 waves/CU (the 64KB-LDS cap) -> VGPR budget 256.
// ---------------------------------------------------------------------------
// byte offset into swizzled B tile: row-major [128][512B], 16B-unit XOR swizzle
#define BSWZ(r, cb) (((r) << 9) + ((cb) ^ (((r) & 7) << 4)))

__global__ __launch_bounds__(256, 2) void gemm_mfma_value(
    const float* __restrict__ A, const ushort* __restrict__ Bt,
    const float* __restrict__ bias, ushort* __restrict__ C, int M)
{
    __shared__ ushort Bs[128 * 256];          // 64 KB, swizzled
    char* bs = (char*)Bs;
    const int tid  = threadIdx.x;
    const int wave = tid >> 6, lane = tid & 63;
    const int bm = blockIdx.x * 128;
    const int bn = blockIdx.y * 128;
    const int wm = (wave >> 1) * 64, wn = (wave & 1) * 64;

    // ---- one-time: stage B tile (128 n-rows x 256 k) into LDS, swizzled ----
    #pragma unroll
    for (int it = 0; it < 16; ++it) {
        int idx = it * 256 + tid;             // 0..4095 16B-chunks
        int r   = idx >> 5;                   // n-row 0..127
        int c8  = idx & 31;                   // 16B chunk within row
        ushort8 v = *(const ushort8*)(Bt + (size_t)(bn + r) * CC + c8 * 8);
        *(ushort8*)(bs + BSWZ(r, c8 * 16)) = v;
    }
    __syncthreads();

    f32x4 acc[4][4] = {};
    const int fr = lane & 15, kg = lane >> 4;
    const float* aA = A + (size_t)(bm + wm + fr) * CC + kg * 8;

    // explicit 2-deep ping-pong prefetch (named buffers => static indexing)
    float4 pA[4][2], pB[4][2];
    #pragma unroll
    for (int i = 0; i < 4; ++i) {
        const float* ap = aA + (size_t)(i * 16) * CC;      // kt = 0
        pA[i][0] = *(const float4*)(ap);
        pA[i][1] = *(const float4*)(ap + 4);
    }
    #pragma unroll
    for (int i = 0; i < 4; ++i) {
        const float* ap = aA + (size_t)(i * 16) * CC + 32; // kt = 1
        pB[i][0] = *(const float4*)(ap);
        pB[i][1] = *(const float4*)(ap + 4);
    }

    #pragma unroll
    for (int kt = 0; kt < 8; kt += 2) {
        // ================= even step: consume pA (kt), refill with kt+2 =====
        {
            bf16x8 bfv[4];
            #pragma unroll
            for (int j = 0; j < 4; ++j)
                bfv[j] = *(const bf16x8*)(bs + BSWZ(wn + j * 16 + fr, kt * 64 + kg * 16));
            bf16x8 af[4];
            #pragma unroll
            for (int i = 0; i < 4; ++i) {
                ushort8 u;
                u[0] = f2bf(pA[i][0].x); u[1] = f2bf(pA[i][0].y);
                u[2] = f2bf(pA[i][0].z); u[3] = f2bf(pA[i][0].w);
                u[4] = f2bf(pA[i][1].x); u[5] = f2bf(pA[i][1].y);
                u[6] = f2bf(pA[i][1].z); u[7] = f2bf(pA[i][1].w);
                af[i] = __builtin_bit_cast(bf16x8, u);
            }
            if (kt + 2 < 8) {
                #pragma unroll
                for (int i = 0; i < 4; ++i) {
                    const float* ap = aA + (size_t)(i * 16) * CC + (kt + 2) * 32;
                    pA[i][0] = *(const float4*)(ap);
                    pA[i][1] = *(const float4*)(ap + 4);
                }
            }
            #pragma unroll
            for (int i = 0; i < 4; ++i)
                #pragma unroll
                for (int j = 0; j < 4; ++j)
                    acc[i][j] = __builtin_amdgcn_mfma_f32_16x16x32_bf16(af[i], bfv[j], acc[i][j], 0, 0, 0);
        }
        // ================= odd step: consume pB (kt+1), refill with kt+3 ====
        {
            bf16x8 bfv[4];
            #pragma unroll
            for (int j = 0; j < 4; ++j)
                bfv[j] = *(const bf16x8*)(bs + BSWZ(wn + j * 16 + fr, (kt + 1) * 64 + kg * 16));
            bf16x8 af[4];
            #pragma unroll
            for (int i = 0; i < 4; ++i) {
                ushort8 u;
                u[0] = f2bf(pB[i][0].x); u[1] = f2bf(pB[i][0].y);
                u[2] = f2bf(pB[i][0].z); u[3] = f2bf(pB[i][0].w);
                u[4] = f2bf(pB[i][1].x); u[5] = f2bf(pB[i][1].y);
                u[6] = f2bf(pB[i][1].z); u[7] = f2bf(pB[i][1].w);
                af[i] = __builtin_bit_cast(bf16x8, u);
            }
            if (kt + 3 < 8) {
                #pragma unroll
                for (int i = 0; i < 4; ++i) {
                    const float* ap = aA + (size_t)(i * 16) * CC + (kt + 3) * 32;
                    pB[i][0] = *(const float4*)(ap);
                    pB[i][1] = *(const float4*)(ap + 4);
                }
            }
            #pragma unroll
            for (int i = 0; i < 4; ++i)
                #pragma unroll
                for (int j = 0; j < 4; ++j)
                    acc[i][j] = __builtin_amdgcn_mfma_f32_16x16x32_bf16(af[i], bfv[j], acc[i][j], 0, 0, 0);
        }
    }

    const int col0 = lane & 15, rq = (lane >> 4) * 4;
    #pragma unroll
    for (int j = 0; j < 4; ++j) {
        const int col = bn + wn + j * 16 + col0;
        const float bv = bias[col];
        #pragma unroll
        for (int i = 0; i < 4; ++i) {
            const int row = bm + wm + i * 16 + rq;
            #pragma unroll
            for (int r = 0; r < 4; ++r)
                C[(size_t)(row + r) * CC + col] = f2bf(acc[i][j][r] + bv);
        }
    }
}

// ---------------------------------------------------------------------------
// Generic tiled f32 GEMM with bias (small GEMMs)
// ---------------------------------------------------------------------------
#define TM 64
#define TN 64
#define TK 16

__global__ __launch_bounds__(256) void gemm_bias_kernel(
    const float* __restrict__ A, const float* __restrict__ B,
    const float* __restrict__ bias, float* __restrict__ Cmat,
    int M, int N, int K)
{
    __shared__ float As[TK][TM + 4];
    __shared__ float Bs[TK][TN + 4];
    const int tid = threadIdx.x;
    const int bm = blockIdx.x * TM;
    const int bn = blockIdx.y * TN;
    const int tm = (tid >> 4) << 2;
    const int tn = (tid & 15) << 2;
    float acc[4][4] = {};

    for (int k0 = 0; k0 < K; k0 += TK) {
        #pragma unroll
        for (int i = 0; i < 4; ++i) {
            int idx = tid + i * 256;
            int m = idx >> 4;
            int k = idx & 15;
            int gm = bm + m;
            float v = 0.f;
            if (gm < M) v = A[(size_t)gm * K + k0 + k];
            As[k][m] = v;
        }
        #pragma unroll
        for (int i = 0; i < 4; ++i) {
            int idx = tid + i * 256;
            int k = idx >> 6;
            int n = idx & 63;
            int gn = bn + n;
            float v = 0.f;
            if (gn < N) v = B[(size_t)(k0 + k) * N + gn];
            Bs[k][n] = v;
        }
        __syncthreads();
        #pragma unroll
        for (int k = 0; k < TK; ++k) {
            float a[4], b[4];
            #pragma unroll
            for (int i = 0; i < 4; ++i) a[i] = As[k][tm + i];
            #pragma unroll
            for (int j = 0; j < 4; ++j) b[j] = Bs[k][tn + j];
            #pragma unroll
            for (int i = 0; i < 4; ++i)
                #pragma unroll
                for (int j = 0; j < 4; ++j)
                    acc[i][j] = fmaf(a[i], b[j], acc[i][j]);
        }
        __syncthreads();
    }

    #pragma unroll
    for (int i = 0; i < 4; ++i) {
        int m = bm + tm + i;
        if (m >= M) continue;
        #pragma unroll
        for (int j = 0; j < 4; ++j) {
            int n = bn + tn + j;
            if (n < N) Cmat[(size_t)m * N + n] = acc[i][j] + bias[n];
        }
    }
}

// ---------------------------------------------------------------------------
// bbox kernel: one block per (n,q); scan 128x128 mask, write box[4] to ws.
// ---------------------------------------------------------------------------
__global__ __launch_bounds__(256) void bbox_kernel(
    const float* __restrict__ masks, float* __restrict__ boxes)
{
    const int b   = blockIdx.x;
    const int tid = threadIdx.x;
    const float4* m4 = (const float4*)(masks + (size_t)b * (MH * MW));

    int wmin = MW, wmax = -1, hmin = MH, hmax = -1;
    #pragma unroll
    for (int it = 0; it < 16; ++it) {
        int i = tid + it * 256;
        float4 v = m4[i];
        int base = i << 2;
        int h = base >> 7;
        int w0 = base & 127;
        bool a0 = v.x > 0.f, a1 = v.y > 0.f, a2 = v.z > 0.f, a3 = v.w > 0.f;
        if (a0 | a1 | a2 | a3) { hmin = min(hmin, h); hmax = max(hmax, h); }
        if (a0) { wmin = min(wmin, w0);     wmax = max(wmax, w0);     }
        if (a1) { wmin = min(wmin, w0 + 1); wmax = max(wmax, w0 + 1); }
        if (a2) { wmin = min(wmin, w0 + 2); wmax = max(wmax, w0 + 2); }
        if (a3) { wmin = min(wmin, w0 + 3); wmax = max(wmax, w0 + 3); }
    }
    #pragma unroll
    for (int off = 32; off; off >>= 1) {
        wmin = min(wmin, __shfl_xor(wmin, off));
        wmax = max(wmax, __shfl_xor(wmax, off));
        hmin = min(hmin, __shfl_xor(hmin, off));
        hmax = max(hmax, __shfl_xor(hmax, off));
    }
    __shared__ int s_wmin[4], s_wmax[4], s_hmin[4], s_hmax[4];
    const int wave = tid >> 6;
    if ((tid & 63) == 0) {
        s_wmin[wave] = wmin; s_wmax[wave] = wmax;
        s_hmin[wave] = hmin; s_hmax[wave] = hmax;
    }
    __syncthreads();
    if (tid == 0) {
        int a = MW, bx = -1, c = MH, d = -1;
        #pragma unroll
        for (int i = 0; i < 4; ++i) {
            a = min(a, s_wmin[i]); bx = max(bx, s_wmax[i]);
            c = min(c, s_hmin[i]); d = max(d, s_hmax[i]);
        }
        float4 box;
        if (bx >= 0) {
            float x0 = a * (1.f / MW), x1 = (bx + 1) * (1.f / MW);
            float y0 = c * (1.f / MH), y1 = (d + 1) * (1.f / MH);
            box = make_float4((x0 + x1) * 0.5f, (y0 + y1) * 0.5f, x1 - x0, y1 - y0);
        } else {
            box = make_float4(0.f, 0.f, 0.f, 0.f);
        }
        *(float4*)(boxes + (size_t)b * 4) = box;
    }
}

// ---------------------------------------------------------------------------
// Sampling: one block (512 threads) per (n,q). Phase 1 (tid<256): loc, gate,
// softmax. Phase 2: half=tid>>8 handles 2 levels; branchless clamped corner
// loads from bf16 value; LDS reduce across halves.
// ---------------------------------------------------------------------------
template<int WL>
static __device__ __forceinline__ float sample_level(
    const ushort* __restrict__ vbase, int st,
    const float* __restrict__ s_lx, const float* __restrict__ s_ly,
    const float* __restrict__ s_w, int ptbase)
{
    float acc = 0.f;
    #pragma unroll
    for (int p = 0; p < NPTS; ++p) {
        const int pt = ptbase + p;
        const float fx = s_lx[pt] * WL - 0.5f;
        const float fy = s_ly[pt] * WL - 0.5f;
        const float pw = s_w[pt];
        const float x0f = floorf(fx), y0f = floorf(fy);
        const float wx = fx - x0f, wy = fy - y0f;
        const int x0 = (int)x0f, y0 = (int)y0f;
        const int x1 = x0 + 1, y1 = y0 + 1;
        const int x0c = min(max(x0, 0), WL - 1);
        const int x1c = min(max(x1, 0), WL - 1);
        const int y0c = min(max(y0, 0), WL - 1);
        const int y1c = min(max(y1, 0), WL - 1);
        const float vx0 = (x0 >= 0 && x0 < WL) ? 1.f : 0.f;
        const float vx1 = (x1 >= 0 && x1 < WL) ? 1.f : 0.f;
        const float vy0 = (y0 >= 0 && y0 < WL) ? 1.f : 0.f;
        const float vy1 = (y1 >= 0 && y1 < WL) ? 1.f : 0.f;
        const ushort* r0 = vbase + (size_t)(st + y0c * WL) * CC;
        const ushort* r1 = vbase + (size_t)(st + y1c * WL) * CC;
        const float v00 = bf2f(r0[(size_t)x0c * CC]);
        const float v01 = bf2f(r0[(size_t)x1c * CC]);
        const float v10 = bf2f(r1[(size_t)x0c * CC]);
        const float v11 = bf2f(r1[(size_t)x1c * CC]);
        const float w00 = vx0 * vy0 * (1.f - wx) * (1.f - wy);
        const float w01 = vx1 * vy0 * wx * (1.f - wy);
        const float w10 = vx0 * vy1 * (1.f - wx) * wy;
        const float w11 = vx1 * vy1 * wx * wy;
        acc += pw * (w00 * v00 + w01 * v01 + w10 * v10 + w11 * v11);
    }
    return acc;
}

__global__ __launch_bounds__(512) void sample_kernel(
    const float* __restrict__ masks,   // (NQ, 128*128)
    const ushort* __restrict__ value,  // (NB, LEN_IN, 256) bf16
    const float* __restrict__ offs,    // (NQ, 512)
    const float* __restrict__ attw,    // (NQ, 256)
    const float* __restrict__ boxes,   // (NQ, 4)
    float* __restrict__ samp)          // (NQ, 256)
{
    const int b   = blockIdx.x;
    const int n   = b / LQ;
    const int tid = threadIdx.x;

    __shared__ float s_lx[256], s_ly[256], s_w[256], s_acc[256];

    if (tid < 256) {
        const float4 box = *(const float4*)(boxes + (size_t)b * 4);
        const float ox = offs[(size_t)b * 512 + tid * 2 + 0];
        const float oy = offs[(size_t)b * 512 + tid * 2 + 1];
        const float lx = box.x + ox * (1.f / NPTS) * box.z * 0.5f;
        const float ly = box.y + oy * (1.f / NPTS) * box.w * 0.5f;
        int px = (int)(lx * MW); px = min(max(px, 0), MW - 1);
        int py = (int)(ly * MH); py = min(max(py, 0), MH - 1);
        const float pin = (masks[(size_t)b * (MH * MW) + py * MW + px] > 0.f) ? 1.f : 0.f;
        const float logit = attw[(size_t)b * 256 + tid] * pin;
        float mx = logit;
        #pragma unroll
        for (int off = 16; off; off >>= 1) mx = fmaxf(mx, __shfl_xor(mx, off, 32));
        const float e = expf(logit - mx);
        float ssum = e;
        #pragma unroll
        for (int off = 16; off; off >>= 1) ssum += __shfl_xor(ssum, off, 32);
        s_lx[tid] = lx; s_ly[tid] = ly; s_w[tid] = e / ssum;
    }
    __syncthreads();

    const int half = tid >> 8;
    const int h = (tid >> 5) & 7, d = tid & 31;
    const ushort* vbase = value + (size_t)n * LEN_IN * CC + h * DH + d;
    float acc;
    if (half == 0) {
        acc  = sample_level<128>(vbase, 0,     s_lx, s_ly, s_w, (h * NLVL + 0) * NPTS);
        acc += sample_level< 64>(vbase, 16384, s_lx, s_ly, s_w, (h * NLVL + 1) * NPTS);
        s_acc[tid] = acc;
    } else {
        acc  = sample_level< 32>(vbase, 20480, s_lx, s_ly, s_w, (h * NLVL + 2) * NPTS);
        acc += sample_level< 16>(vbase, 21504, s_lx, s_ly, s_w, (h * NLVL + 3) * NPTS);
    }
    __syncthreads();
    if (half == 1)
        samp[(size_t)b * 256 + (tid - 256)] = acc + s_acc[tid - 256];
}

// ---------------------------------------------------------------------------
extern "C" void kernel_launch(void* const* d_in, const int* in_sizes, int n_in,
                              void* d_out, int out_size, void* d_ws, size_t ws_size,
                              hipStream_t stream)
{
    const float* query  = (const float*)d_in[0];
    const float* masks  = (const float*)d_in[2];
    const float* flat   = (const float*)d_in[4];
    const float* W_off  = (const float*)d_in[8];
    const float* b_off  = (const float*)d_in[9];
    const float* W_attn = (const float*)d_in[10];
    const float* b_attn = (const float*)d_in[11];
    const float* W_val  = (const float*)d_in[12];
    const float* b_val  = (const float*)d_in[13];
    const float* W_out  = (const float*)d_in[14];
    const float* b_out  = (const float*)d_in[15];
    float* out = (float*)d_out;

    float*  offs  = (float*)d_ws;                        // 2400*512
    float*  attw  = offs + (size_t)NQ * 512;             // 2400*256
    float*  samp  = attw + (size_t)NQ * 256;             // 2400*256
    float*  boxes = samp + (size_t)NQ * 256;             // 2400*4
    ushort* value = (ushort*)(boxes + (size_t)NQ * 4);   // 174080*256 bf16
    ushort* Bt    = value + (size_t)NB * LEN_IN * CC;    // 256*256 bf16

    const int Mval = NB * LEN_IN;                        // 174080

    transpose_cast_w<<<CC, CC, 0, stream>>>(W_val, Bt);
    gemm_mfma_value<<<dim3(Mval / 128, CC / 128), 256, 0, stream>>>(
        flat, Bt, b_val, value, Mval);
    gemm_bias_kernel<<<dim3((NQ + TM - 1) / TM, 512 / TN), 256, 0, stream>>>(
        query, W_off, b_off, offs, NQ, 512, CC);
    gemm_bias_kernel<<<dim3((NQ + TM - 1) / TM, CC / TN), 256, 0, stream>>>(
        query, W_attn, b_attn, attw, NQ, CC, CC);
    bbox_kernel<<<NQ, 256, 0, stream>>>(masks, boxes);
    sample_kernel<<<NQ, 512, 0, stream>>>(masks, value, offs, attw, boxes, samp);
    gemm_bias_kernel<<<dim3((NQ + TM - 1) / TM, CC / TN), 256, 0, stream>>>(
        samp, W_out, b_out, out, NQ, CC, CC);
}

// Round 4
// 584.190 us; speedup vs baseline: 1.0460x; 1.0409x over previous
//
#include <hip/hip_runtime.h>
#include <math.h>

#define NB    8
#define LQ    300
#define CC    256
#define HEADS 8
#define NLVL  4
#define NPTS  8
#define DH    32
#define LEN_IN 21760
#define NQ    (NB*LQ)     // 2400
#define MH    128
#define MW    128

typedef __attribute__((ext_vector_type(8))) short bf16x8;
typedef __attribute__((ext_vector_type(8))) unsigned short ushort8;
typedef __attribute__((ext_vector_type(4))) float f32x4;
typedef unsigned short ushort;
typedef unsigned int uint;

#define AS1 __attribute__((address_space(1)))
#define AS3 __attribute__((address_space(3)))

static __device__ __forceinline__ ushort f2bf(float f) {
    uint u = __builtin_bit_cast(uint, f);
    uint r = (u + 0x7fffu + ((u >> 16) & 1u)) >> 16;   // RNE
    return (ushort)r;
}
static __device__ __forceinline__ float bf2f(ushort u) {
    return __builtin_bit_cast(float, ((uint)u) << 16);
}

// ---------------------------------------------------------------------------
// W_val (k-major 256x256 f32) -> Bt (n-major 256x256 bf16)
// ---------------------------------------------------------------------------
__global__ void transpose_cast_w(const float* __restrict__ W, ushort* __restrict__ Bt) {
    int n = blockIdx.x, k = threadIdx.x;
    Bt[n * CC + k] = f2bf(W[(size_t)k * CC + n]);
}

// ---------------------------------------------------------------------------
// MFMA value GEMM: value[M,256](bf16) = A[M,256](f32) @ W + bias.
// 512 thr / 8 waves, block tile 256m x 128n, grid (M/256, 2).
// B half-tile (64KB bf16, XOR-swizzled) resident in LDS, staged once.
// A staged f32 -> LDS via global_load_lds (width 16), double-buffered
// 2x32KB, source-address-swizzled (chunk c of row r lands at slot c^(r&7)).
// K-loop: counted vmcnt(4) (never 0 until last tile) + raw s_barrier pair;
// 4 global_load_lds per wave per kt stay in flight across barriers (T3+T4).
// Bias folded into acc init (loaded FIRST so in-order vmcnt retires it
// before the loop; no VMEM inside the counted region).
// ---------------------------------------------------------------------------
// byte offset into swizzled B tile: row-major [128][512B], 16B-unit XOR swizzle
#define BSWZ(r, cb) (((r) << 9) + ((cb) ^ (((r) & 7) << 4)))

__global__ __launch_bounds__(512, 1) void gemm_mfma_value(
    const float* __restrict__ A, const ushort* __restrict__ Bt,
    const float* __restrict__ bias, ushort* __restrict__ C, int M)
{
    __shared__ ushort Bs[128 * 256];      // 64 KB, swizzled (BSWZ)
    __shared__ float  As[2][256 * 32];    // 2 x 32 KB, source-swizzled
    char* bs = (char*)Bs;
    const int tid  = threadIdx.x;
    const int wave = tid >> 6, lane = tid & 63;
    const int bm = blockIdx.x * 256;
    const int bn = blockIdx.y * 128;
    const int wm = (wave >> 1) * 64, wn = (wave & 1) * 64;
    const int fr = lane & 15, kg = lane >> 4;
    const int col0 = lane & 15;

    // ---- bias FIRST: in-order vmcnt retirement => complete before loop ----
    float bv[4];
    #pragma unroll
    for (int j = 0; j < 4; ++j) bv[j] = bias[bn + wn + j * 16 + col0];

    // ---- stage B half-tile (128 n-rows x 256 k bf16) swizzled (reg-staged)
    #pragma unroll
    for (int it = 0; it < 8; ++it) {
        int idx = it * 512 + tid;         // 0..4095 16B-chunks
        int r   = idx >> 5;               // n-row 0..127
        int c8  = idx & 31;               // 16B chunk within row
        ushort8 v = *(const ushort8*)(Bt + (size_t)(bn + r) * CC + c8 * 8);
        *(ushort8*)(bs + BSWZ(r, c8 * 16)) = v;
    }

    // ---- acc init = bias (consumes bv; adds bias exactly once) ----
    f32x4 acc[4][4];
    #pragma unroll
    for (int i = 0; i < 4; ++i)
        #pragma unroll
        for (int j = 0; j < 4; ++j)
            acc[i][j] = (f32x4){bv[j], bv[j], bv[j], bv[j]};

    __syncthreads();   // Bs visible to all waves; A-DMA not yet issued

    // ---- A tile staging: 4 x global_load_lds per wave per kt ----
    // chunk idx (16B units) = r*8 + c' with c' = c ^ (r&7); lane l writes
    // LDS base+l*16, so lane fetches global chunk c = (idx&7) ^ (r&7).
    #define STAGE_A(KT, DST)                                                   \
        {                                                                      \
            _Pragma("unroll")                                                  \
            for (int t = 0; t < 4; ++t) {                                      \
                int bi  = (wave * 4 + t) * 64;                                 \
                int idx = bi + lane;                                           \
                int r   = idx >> 3;                                            \
                int c   = (idx & 7) ^ (r & 7);                                 \
                const float* g = A + (size_t)(bm + r) * CC + (KT) * 32 + c * 4;\
                __builtin_amdgcn_global_load_lds((const AS1 void*)g,           \
                    (AS3 void*)((AS3 char*)(DST) + bi * 16), 16, 0, 0);        \
            }                                                                  \
        }

    STAGE_A(0, &As[0][0]);
    STAGE_A(1, &As[1][0]);

    #pragma unroll
    for (int kt = 0; kt < 8; ++kt) {
        // wait for current buffer's own loads (4 outstanding = next tile's)
        if (kt < 7) { asm volatile("s_waitcnt vmcnt(4)" ::: "memory"); }
        else        { asm volatile("s_waitcnt vmcnt(0)" ::: "memory"); }
        __builtin_amdgcn_s_barrier();          // all waves: cur tile staged

        const float* ab = &As[kt & 1][0];
        float4 a0[4], a1[4];
        #pragma unroll
        for (int i = 0; i < 4; ++i) {
            int rr = wm + i * 16 + fr;
            int i0 = rr * 8 + ((kg * 2 + 0) ^ (rr & 7));
            int i1 = rr * 8 + ((kg * 2 + 1) ^ (rr & 7));
            a0[i] = *(const float4*)(ab + i0 * 4);
            a1[i] = *(const float4*)(ab + i1 * 4);
        }
        bf16x8 bfv[4];
        #pragma unroll
        for (int j = 0; j < 4; ++j)
            bfv[j] = *(const bf16x8*)(bs + BSWZ(wn + j * 16 + fr, kt * 64 + kg * 16));

        asm volatile("s_waitcnt lgkmcnt(0)" ::: "memory");
        __builtin_amdgcn_s_barrier();          // all waves done reading cur

        if (kt + 2 < 8) STAGE_A(kt + 2, &As[kt & 1][0]);   // refill freed buf

        bf16x8 af[4];
        #pragma unroll
        for (int i = 0; i < 4; ++i) {
            ushort8 u;
            u[0] = f2bf(a0[i].x); u[1] = f2bf(a0[i].y);
            u[2] = f2bf(a0[i].z); u[3] = f2bf(a0[i].w);
            u[4] = f2bf(a1[i].x); u[5] = f2bf(a1[i].y);
            u[6] = f2bf(a1[i].z); u[7] = f2bf(a1[i].w);
            af[i] = __builtin_bit_cast(bf16x8, u);
        }
        #pragma unroll
        for (int i = 0; i < 4; ++i)
            #pragma unroll
            for (int j = 0; j < 4; ++j)
                acc[i][j] = __builtin_amdgcn_mfma_f32_16x16x32_bf16(af[i], bfv[j], acc[i][j], 0, 0, 0);
    }
    __builtin_amdgcn_sched_barrier(0);  // keep epilogue stores out of the counted region

    const int rq = (lane >> 4) * 4;
    #pragma unroll
    for (int j = 0; j < 4; ++j) {
        const int col = bn + wn + j * 16 + col0;
        #pragma unroll
        for (int i = 0; i < 4; ++i) {
            const int row = bm + wm + i * 16 + rq;
            #pragma unroll
            for (int r = 0; r < 4; ++r)
                C[(size_t)(row + r) * CC + col] = f2bf(acc[i][j][r]);
        }
    }
    #undef STAGE_A
}

// ---------------------------------------------------------------------------
// Generic tiled f32 GEMM with bias (small GEMMs)
// ---------------------------------------------------------------------------
#define TM 64
#define TN 64
#define TK 16

__global__ __launch_bounds__(256) void gemm_bias_kernel(
    const float* __restrict__ A, const float* __restrict__ B,
    const float* __restrict__ bias, float* __restrict__ Cmat,
    int M, int N, int K)
{
    __shared__ float As[TK][TM + 4];
    __shared__ float Bs[TK][TN + 4];
    const int tid = threadIdx.x;
    const int bm = blockIdx.x * TM;
    const int bn = blockIdx.y * TN;
    const int tm = (tid >> 4) << 2;
    const int tn = (tid & 15) << 2;
    float acc[4][4] = {};

    for (int k0 = 0; k0 < K; k0 += TK) {
        #pragma unroll
        for (int i = 0; i < 4; ++i) {
            int idx = tid + i * 256;
            int m = idx >> 4;
            int k = idx & 15;
            int gm = bm + m;
            float v = 0.f;
            if (gm < M) v = A[(size_t)gm * K + k0 + k];
            As[k][m] = v;
        }
        #pragma unroll
        for (int i = 0; i < 4; ++i) {
            int idx = tid + i * 256;
            int k = idx >> 6;
            int n = idx & 63;
            int gn = bn + n;
            float v = 0.f;
            if (gn < N) v = B[(size_t)(k0 + k) * N + gn];
            Bs[k][n] = v;
        }
        __syncthreads();
        #pragma unroll
        for (int k = 0; k < TK; ++k) {
            float a[4], b[4];
            #pragma unroll
            for (int i = 0; i < 4; ++i) a[i] = As[k][tm + i];
            #pragma unroll
            for (int j = 0; j < 4; ++j) b[j] = Bs[k][tn + j];
            #pragma unroll
            for (int i = 0; i < 4; ++i)
                #pragma unroll
                for (int j = 0; j < 4; ++j)
                    acc[i][j] = fmaf(a[i], b[j], acc[i][j]);
        }
        __syncthreads();
    }

    #pragma unroll
    for (int i = 0; i < 4; ++i) {
        int m = bm + tm + i;
        if (m >= M) continue;
        #pragma unroll
        for (int j = 0; j < 4; ++j) {
            int n = bn + tn + j;
            if (n < N) Cmat[(size_t)m * N + n] = acc[i][j] + bias[n];
        }
    }
}

// ---------------------------------------------------------------------------
// bbox kernel: one block per (n,q); scan 128x128 mask, write box[4] to ws.
// ---------------------------------------------------------------------------
__global__ __launch_bounds__(256) void bbox_kernel(
    const float* __restrict__ masks, float* __restrict__ boxes)
{
    const int b   = blockIdx.x;
    const int tid = threadIdx.x;
    const float4* m4 = (const float4*)(masks + (size_t)b * (MH * MW));

    int wmin = MW, wmax = -1, hmin = MH, hmax = -1;
    #pragma unroll
    for (int it = 0; it < 16; ++it) {
        int i = tid + it * 256;
        float4 v = m4[i];
        int base = i << 2;
        int h = base >> 7;
        int w0 = base & 127;
        bool a0 = v.x > 0.f, a1 = v.y > 0.f, a2 = v.z > 0.f, a3 = v.w > 0.f;
        if (a0 | a1 | a2 | a3) { hmin = min(hmin, h); hmax = max(hmax, h); }
        if (a0) { wmin = min(wmin, w0);     wmax = max(wmax, w0);     }
        if (a1) { wmin = min(wmin, w0 + 1); wmax = max(wmax, w0 + 1); }
        if (a2) { wmin = min(wmin, w0 + 2); wmax = max(wmax, w0 + 2); }
        if (a3) { wmin = min(wmin, w0 + 3); wmax = max(wmax, w0 + 3); }
    }
    #pragma unroll
    for (int off = 32; off; off >>= 1) {
        wmin = min(wmin, __shfl_xor(wmin, off));
        wmax = max(wmax, __shfl_xor(wmax, off));
        hmin = min(hmin, __shfl_xor(hmin, off));
        hmax = max(hmax, __shfl_xor(hmax, off));
    }
    __shared__ int s_wmin[4], s_wmax[4], s_hmin[4], s_hmax[4];
    const int wave = tid >> 6;
    if ((tid & 63) == 0) {
        s_wmin[wave] = wmin; s_wmax[wave] = wmax;
        s_hmin[wave] = hmin; s_hmax[wave] = hmax;
    }
    __syncthreads();
    if (tid == 0) {
        int a = MW, bx = -1, c = MH, d = -1;
        #pragma unroll
        for (int i = 0; i < 4; ++i) {
            a = min(a, s_wmin[i]); bx = max(bx, s_wmax[i]);
            c = min(c, s_hmin[i]); d = max(d, s_hmax[i]);
        }
        float4 box;
        if (bx >= 0) {
            float x0 = a * (1.f / MW), x1 = (bx + 1) * (1.f / MW);
            float y0 = c * (1.f / MH), y1 = (d + 1) * (1.f / MH);
            box = make_float4((x0 + x1) * 0.5f, (y0 + y1) * 0.5f, x1 - x0, y1 - y0);
        } else {
            box = make_float4(0.f, 0.f, 0.f, 0.f);
        }
        *(float4*)(boxes + (size_t)b * 4) = box;
    }
}

// ---------------------------------------------------------------------------
// Sampling: one block (512 threads) per (n,q). Phase 1 (tid<256): loc, gate,
// softmax. Phase 2: half=tid>>8 handles 2 levels; branchless clamped corner
// loads from bf16 value; LDS reduce across halves.
// ---------------------------------------------------------------------------
template<int WL>
static __device__ __forceinline__ float sample_level(
    const ushort* __restrict__ vbase, int st,
    const float* __restrict__ s_lx, const float* __restrict__ s_ly,
    const float* __restrict__ s_w, int ptbase)
{
    float acc = 0.f;
    #pragma unroll
    for (int p = 0; p < NPTS; ++p) {
        const int pt = ptbase + p;
        const float fx = s_lx[pt] * WL - 0.5f;
        const float fy = s_ly[pt] * WL - 0.5f;
        const float pw = s_w[pt];
        const float x0f = floorf(fx), y0f = floorf(fy);
        const float wx = fx - x0f, wy = fy - y0f;
        const int x0 = (int)x0f, y0 = (int)y0f;
        const int x1 = x0 + 1, y1 = y0 + 1;
        const int x0c = min(max(x0, 0), WL - 1);
        const int x1c = min(max(x1, 0), WL - 1);
        const int y0c = min(max(y0, 0), WL - 1);
        const int y1c = min(max(y1, 0), WL - 1);
        const float vx0 = (x0 >= 0 && x0 < WL) ? 1.f : 0.f;
        const float vx1 = (x1 >= 0 && x1 < WL) ? 1.f : 0.f;
        const float vy0 = (y0 >= 0 && y0 < WL) ? 1.f : 0.f;
        const float vy1 = (y1 >= 0 && y1 < WL) ? 1.f : 0.f;
        const ushort* r0 = vbase + (size_t)(st + y0c * WL) * CC;
        const ushort* r1 = vbase + (size_t)(st + y1c * WL) * CC;
        const float v00 = bf2f(r0[(size_t)x0c * CC]);
        const float v01 = bf2f(r0[(size_t)x1c * CC]);
        const float v10 = bf2f(r1[(size_t)x0c * CC]);
        const float v11 = bf2f(r1[(size_t)x1c * CC]);
        const float w00 = vx0 * vy0 * (1.f - wx) * (1.f - wy);
        const float w01 = vx1 * vy0 * wx * (1.f - wy);
        const float w10 = vx0 * vy1 * (1.f - wx) * wy;
        const float w11 = vx1 * vy1 * wx * wy;
        acc += pw * (w00 * v00 + w01 * v01 + w10 * v10 + w11 * v11);
    }
    return acc;
}

__global__ __launch_bounds__(512) void sample_kernel(
    const float* __restrict__ masks,   // (NQ, 128*128)
    const ushort* __restrict__ value,  // (NB, LEN_IN, 256) bf16
    const float* __restrict__ offs,    // (NQ, 512)
    const float* __restrict__ attw,    // (NQ, 256)
    const float* __restrict__ boxes,   // (NQ, 4)
    float* __restrict__ samp)          // (NQ, 256)
{
    const int b   = blockIdx.x;
    const int n   = b / LQ;
    const int tid = threadIdx.x;

    __shared__ float s_lx[256], s_ly[256], s_w[256], s_acc[256];

    if (tid < 256) {
        const float4 box = *(const float4*)(boxes + (size_t)b * 4);
        const float ox = offs[(size_t)b * 512 + tid * 2 + 0];
        const float oy = offs[(size_t)b * 512 + tid * 2 + 1];
        const float lx = box.x + ox * (1.f / NPTS) * box.z * 0.5f;
        const float ly = box.y + oy * (1.f / NPTS) * box.w * 0.5f;
        int px = (int)(lx * MW); px = min(max(px, 0), MW - 1);
        int py = (int)(ly * MH); py = min(max(py, 0), MH - 1);
        const float pin = (masks[(size_t)b * (MH * MW) + py * MW + px] > 0.f) ? 1.f : 0.f;
        const float logit = attw[(size_t)b * 256 + tid] * pin;
        float mx = logit;
        #pragma unroll
        for (int off = 16; off; off >>= 1) mx = fmaxf(mx, __shfl_xor(mx, off, 32));
        const float e = expf(logit - mx);
        float ssum = e;
        #pragma unroll
        for (int off = 16; off; off >>= 1) ssum += __shfl_xor(ssum, off, 32);
        s_lx[tid] = lx; s_ly[tid] = ly; s_w[tid] = e / ssum;
    }
    __syncthreads();

    const int half = tid >> 8;
    const int h = (tid >> 5) & 7, d = tid & 31;
    const ushort* vbase = value + (size_t)n * LEN_IN * CC + h * DH + d;
    float acc;
    if (half == 0) {
        acc  = sample_level<128>(vbase, 0,     s_lx, s_ly, s_w, (h * NLVL + 0) * NPTS);
        acc += sample_level< 64>(vbase, 16384, s_lx, s_ly, s_w, (h * NLVL + 1) * NPTS);
        s_acc[tid] = acc;
    } else {
        acc  = sample_level< 32>(vbase, 20480, s_lx, s_ly, s_w, (h * NLVL + 2) * NPTS);
        acc += sample_level< 16>(vbase, 21504, s_lx, s_ly, s_w, (h * NLVL + 3) * NPTS);
    }
    __syncthreads();
    if (half == 1)
        samp[(size_t)b * 256 + (tid - 256)] = acc + s_acc[tid - 256];
}

// ---------------------------------------------------------------------------
extern "C" void kernel_launch(void* const* d_in, const int* in_sizes, int n_in,
                              void* d_out, int out_size, void* d_ws, size_t ws_size,
                              hipStream_t stream)
{
    const float* query  = (const float*)d_in[0];
    const float* masks  = (const float*)d_in[2];
    const float* flat   = (const float*)d_in[4];
    const float* W_off  = (const float*)d_in[8];
    const float* b_off  = (const float*)d_in[9];
    const float* W_attn = (const float*)d_in[10];
    const float* b_attn = (const float*)d_in[11];
    const float* W_val  = (const float*)d_in[12];
    const float* b_val  = (const float*)d_in[13];
    const float* W_out  = (const float*)d_in[14];
    const float* b_out  = (const float*)d_in[15];
    float* out = (float*)d_out;

    float*  offs  = (float*)d_ws;                        // 2400*512
    float*  attw  = offs + (size_t)NQ * 512;             // 2400*256
    float*  samp  = attw + (size_t)NQ * 256;             // 2400*256
    float*  boxes = samp + (size_t)NQ * 256;             // 2400*4
    ushort* value = (ushort*)(boxes + (size_t)NQ * 4);   // 174080*256 bf16
    ushort* Bt    = value + (size_t)NB * LEN_IN * CC;    // 256*256 bf16

    const int Mval = NB * LEN_IN;                        // 174080

    transpose_cast_w<<<CC, CC, 0, stream>>>(W_val, Bt);
    gemm_mfma_value<<<dim3(Mval / 256, CC / 128), 512, 0, stream>>>(
        flat, Bt, b_val, value, Mval);
    gemm_bias_kernel<<<dim3((NQ + TM - 1) / TM, 512 / TN), 256, 0, stream>>>(
        query, W_off, b_off, offs, NQ, 512, CC);
    gemm_bias_kernel<<<dim3((NQ + TM - 1) / TM, CC / TN), 256, 0, stream>>>(
        query, W_attn, b_attn, attw, NQ, CC, CC);
    bbox_kernel<<<NQ, 256, 0, stream>>>(masks, boxes);
    sample_kernel<<<NQ, 512, 0, stream>>>(masks, value, offs, attw, boxes, samp);
    gemm_bias_kernel<<<dim3((NQ + TM - 1) / TM, CC / TN), 256, 0, stream>>>(
        samp, W_out, b_out, out, NQ, CC, CC);
}